// Round 2
// baseline (13836.960 us; speedup 1.0000x reference)
//
#include <hip/hip_runtime.h>
#include <math.h>

#define B_ 128
#define T_ 32
#define V_ 30000
#define WD_ 512
#define MF_ 64
#define EWD_ 200
#define HD_ 512
#define DOC_ 500
#define GRU_IN_ 640
#define TB_ 4096     // T*B
#define NG_ 1536     // 3*HD

// ---------------- K1: ud/idoc = mean over DOC of doc_emb[doc] ----------------
__global__ __launch_bounds__(256) void doc_mean_kernel(
    const int* __restrict__ user_doc, const int* __restrict__ item_doc,
    const float* __restrict__ doc_emb, float* __restrict__ ud, float* __restrict__ idoc) {
  int b = blockIdx.x & 127;
  const int* doc = (blockIdx.x < 128) ? user_doc : item_doc;
  float* out = (blockIdx.x < 128) ? ud : idoc;
  int e = threadIdx.x;
  if (e >= EWD_) return;
  const int* row = doc + b * DOC_;
  float acc = 0.f;
#pragma unroll 4
  for (int d = 0; d < DOC_; ++d) {
    acc += doc_emb[row[d] * EWD_ + e];
  }
  out[b * EWD_ + e] = acc * (1.0f / DOC_);
}

// ---------------- K2: rating head ----------------
__global__ __launch_bounds__(64) void rating_kernel(
    const int* __restrict__ user, const int* __restrict__ item, const float* __restrict__ label,
    const float* __restrict__ gamma_user, const float* __restrict__ gamma_item,
    const float* __restrict__ theta_user, const float* __restrict__ theta_item,
    const float* __restrict__ ud, const float* __restrict__ idoc,
    const float* __restrict__ W_tu, const float* __restrict__ W_ti,
    const float* __restrict__ pred_W, const float* __restrict__ pred_b,
    const float* __restrict__ b_users, const float* __restrict__ b_items,
    float* __restrict__ out_rating, float* __restrict__ accs) {
  int b = blockIdx.x;
  int mf = threadIdx.x;  // 64 threads = 1 wave
  int u = user[b], it = item[b];
  float gu = gamma_user[u * MF_ + mf], gi = gamma_item[it * MF_ + mf];
  float tu = theta_user[u * MF_ + mf], ti = theta_item[it * MF_ + mf];
  float du = 0.f, di = 0.f;
#pragma unroll 4
  for (int e = 0; e < EWD_; ++e) {
    du += ud[b * EWD_ + e] * W_tu[mf * EWD_ + e];
    di += idoc[b * EWD_ + e] * W_ti[mf * EWD_ + e];
  }
  float c1 = gu * gi, c2 = tu * du, c3 = ti * di;
  float s = pred_W[mf] * c1 + pred_W[64 + mf] * c2 + pred_W[128 + mf] * c3;
#pragma unroll
  for (int off = 32; off; off >>= 1) s += __shfl_xor(s, off);
  if (mf == 0) {
    float pred = s + pred_b[0] + 3.5f + b_users[u] + b_items[it];
    float d = pred - label[b];
    float loss = d * d;
    out_rating[b] = loss;
    atomicAdd(&accs[0], loss);
  }
}

// ---------------- K3: gi_all = x_seq @ W_ih.T + b_ih (fused gather) ----------------
// M=4096, N=1536, K=640. BM=64, BN=64, BK=32. 256 threads, 4x4 accs/thread.
__global__ __launch_bounds__(256) void xw_gemm_kernel(
    const int* __restrict__ review_input, const int* __restrict__ user, const int* __restrict__ item,
    const float* __restrict__ word_emb, const float* __restrict__ gamma_user,
    const float* __restrict__ gamma_item, const float* __restrict__ W_ih,
    const float* __restrict__ b_ih, float* __restrict__ gi_all) {
  __shared__ float As[64][33];
  __shared__ float Bs[32][68];
  int m0 = (blockIdx.x & 63) * 64;   // 64 m-groups
  int n0 = (blockIdx.x >> 6) * 64;   // 24 n-groups
  int tid = threadIdx.x;
  int tc = tid & 15, tr = tid >> 4;  // 16x16 threads, each 4x4 outputs
  int kl = tid & 31, mb = tid >> 5;  // staging indices
  float acc[4][4] = {};
  for (int k0 = 0; k0 < GRU_IN_; k0 += 32) {
    // stage A (x_seq gathered on the fly): As[m][k]
#pragma unroll
    for (int i = 0; i < 8; ++i) {
      int m = mb + i * 8;
      int r = m0 + m;
      int kg = k0 + kl;
      float v;
      if (kg < WD_) v = word_emb[review_input[r] * WD_ + kg];
      else if (kg < WD_ + MF_) v = gamma_user[user[r & 127] * MF_ + (kg - WD_)];
      else v = gamma_item[item[r & 127] * MF_ + (kg - WD_ - MF_)];
      As[m][kl] = v;
    }
    // stage B: Bs[k][n] = W_ih[n0+n][k0+k]
#pragma unroll
    for (int i = 0; i < 8; ++i) {
      int n = mb + i * 8;
      Bs[kl][n] = W_ih[(n0 + n) * GRU_IN_ + k0 + kl];
    }
    __syncthreads();
#pragma unroll
    for (int k = 0; k < 32; ++k) {
      float4 b4 = *(const float4*)&Bs[k][tc * 4];
      float a0 = As[tr * 4 + 0][k], a1 = As[tr * 4 + 1][k];
      float a2 = As[tr * 4 + 2][k], a3 = As[tr * 4 + 3][k];
      acc[0][0] += a0 * b4.x; acc[0][1] += a0 * b4.y; acc[0][2] += a0 * b4.z; acc[0][3] += a0 * b4.w;
      acc[1][0] += a1 * b4.x; acc[1][1] += a1 * b4.y; acc[1][2] += a1 * b4.z; acc[1][3] += a1 * b4.w;
      acc[2][0] += a2 * b4.x; acc[2][1] += a2 * b4.y; acc[2][2] += a2 * b4.z; acc[2][3] += a2 * b4.w;
      acc[3][0] += a3 * b4.x; acc[3][1] += a3 * b4.y; acc[3][2] += a3 * b4.z; acc[3][3] += a3 * b4.w;
    }
    __syncthreads();
  }
  int n = n0 + tc * 4;
  float4 bb = *(const float4*)&b_ih[n];
#pragma unroll
  for (int i = 0; i < 4; ++i) {
    int r = m0 + tr * 4 + i;
    float4 o;
    o.x = acc[i][0] + bb.x; o.y = acc[i][1] + bb.y;
    o.z = acc[i][2] + bb.z; o.w = acc[i][3] + bb.w;
    *(float4*)&gi_all[(size_t)r * NG_ + n] = o;
  }
}

// ---------------- K4: one GRU step (launched 32x) ----------------
// grid 64 blocks: each handles 8 j-columns x all 128 b. 256 threads.
__global__ __launch_bounds__(256) void gru_step_kernel(
    const float* __restrict__ gi_all, const float* __restrict__ W_hh,
    const float* __restrict__ b_hh, float* __restrict__ hbuf, int t) {
  __shared__ float Hs[64][132];  // [k][b] +4 pad (16B-aligned stride)
  __shared__ float Ws[24][65];   // 3 gates x 8 j rows
  int j0 = blockIdx.x * 8;
  int tid = threadIdx.x;
  int tj = tid & 7, tb = tid >> 3;  // tb in [0,32): b = tb*4+i
  int lane = tid & 63, grp = tid >> 6;
  const float* hprev = hbuf + (size_t)t * B_ * HD_;
  float racc[4] = {}, zacc[4] = {}, nacc[4] = {};
  for (int k0 = 0; k0 < HD_; k0 += 64) {
    // stage h (transposed) : Hs[k][b]
#pragma unroll
    for (int i = 0; i < 32; ++i) {
      int b = grp * 32 + i;
      Hs[lane][b] = hprev[b * HD_ + k0 + lane];
    }
    // stage W_hh rows for gates r,z,n at columns j0..j0+7
#pragma unroll
    for (int i = 0; i < 6; ++i) {
      int rr = grp + i * 4;  // 0..23
      int g = rr >> 3, jj = rr & 7;
      Ws[rr][lane] = W_hh[(g * HD_ + j0 + jj) * HD_ + k0 + lane];
    }
    __syncthreads();
#pragma unroll
    for (int k = 0; k < 64; ++k) {
      float4 h4 = *(const float4*)&Hs[k][tb * 4];
      float wr = Ws[tj][k], wz = Ws[8 + tj][k], wn = Ws[16 + tj][k];
      racc[0] += h4.x * wr; racc[1] += h4.y * wr; racc[2] += h4.z * wr; racc[3] += h4.w * wr;
      zacc[0] += h4.x * wz; zacc[1] += h4.y * wz; zacc[2] += h4.z * wz; zacc[3] += h4.w * wz;
      nacc[0] += h4.x * wn; nacc[1] += h4.y * wn; nacc[2] += h4.z * wn; nacc[3] += h4.w * wn;
    }
    __syncthreads();
  }
  int j = j0 + tj;
  float bh_r = b_hh[j], bh_z = b_hh[HD_ + j], bh_n = b_hh[2 * HD_ + j];
  float* hnext = hbuf + (size_t)(t + 1) * B_ * HD_;
#pragma unroll
  for (int i = 0; i < 4; ++i) {
    int b = tb * 4 + i;
    const float* gi_r = gi_all + (size_t)(t * B_ + b) * NG_;
    float ir = gi_r[j], iz = gi_r[HD_ + j], in_ = gi_r[2 * HD_ + j];
    float rg = 1.f / (1.f + expf(-(ir + racc[i] + bh_r)));
    float zg = 1.f / (1.f + expf(-(iz + zacc[i] + bh_z)));
    float ng = tanhf(in_ + rg * (nacc[i] + bh_n));
    float hp = hprev[b * HD_ + j];
    hnext[b * HD_ + j] = (1.f - zg) * ng + zg * hp;
  }
}

// ---------------- K5: fused vocab GEMM + online LSE ----------------
// grid 512: blockIdx = rg*2 + vs. Each block: 16 rows x one vocab half (15000).
// 256 threads = 4 waves; wave wv owns rows wv*4..+3, 64 lanes x 2 cols (CT=128).
__global__ __launch_bounds__(256) void vocab_lse_kernel(
    const float* __restrict__ hbuf, const float* __restrict__ out_W,
    const float* __restrict__ out_b, const int* __restrict__ review_target,
    float* __restrict__ part) {
  __shared__ float At[WD_][20];   // [k][row] (pad->80B stride, 16B aligned)
  __shared__ float Bs[32][132];   // [k][col]
  int vs = blockIdx.x & 1;
  int rg = blockIdx.x >> 1;       // 0..255
  int r0 = rg * 16;
  int tid = threadIdx.x;
  int lane = tid & 63;
  int wv = tid >> 6;              // wave id 0..3
  int t = r0 >> 7, b0 = r0 & 127; // 16-row groups never cross t
  const float* hrow = hbuf + ((size_t)(t + 1) * B_ + b0) * HD_;
  // stage A transposed (once)
#pragma unroll
  for (int rl = 0; rl < 16; ++rl) {
    At[tid][rl] = hrow[rl * HD_ + tid];
    At[tid + 256][rl] = hrow[rl * HD_ + tid + 256];
  }
  __syncthreads();
  int tgt[4];
  float m[4], ssum[4], tl[4];
#pragma unroll
  for (int i = 0; i < 4; ++i) {
    tgt[i] = review_target[r0 + wv * 4 + i];
    m[i] = -1e30f; ssum[i] = 0.f; tl[i] = -1e30f;
  }
  int vbase = vs * 15000;
  int kk = tid & 31, cb = tid >> 5;  // staging indices
  for (int vc = 0; vc < 118; ++vc) {
    int v0 = vbase + vc * 128;
    int cols = 15000 - vc * 128; if (cols > 128) cols = 128;  // last = 24
    float acc[4][2] = {};
    for (int k0 = 0; k0 < WD_; k0 += 32) {
#pragma unroll
      for (int i = 0; i < 16; ++i) {
        int c = cb + i * 8;
        float v = 0.f;
        if (c < cols) v = out_W[(v0 + c) * WD_ + k0 + kk];
        Bs[kk][c] = v;
      }
      __syncthreads();
#pragma unroll
      for (int k = 0; k < 32; ++k) {
        float4 a4 = *(const float4*)&At[k0 + k][wv * 4];
        float2 b2 = *(const float2*)&Bs[k][lane * 2];
        acc[0][0] += a4.x * b2.x; acc[0][1] += a4.x * b2.y;
        acc[1][0] += a4.y * b2.x; acc[1][1] += a4.y * b2.y;
        acc[2][0] += a4.z * b2.x; acc[2][1] += a4.z * b2.y;
        acc[3][0] += a4.w * b2.x; acc[3][1] += a4.w * b2.y;
      }
      __syncthreads();
    }
    // online LSE update (per wave-owned row)
#pragma unroll
    for (int i = 0; i < 4; ++i) {
      float lg[2];
#pragma unroll
      for (int j = 0; j < 2; ++j) {
        int c = lane * 2 + j;
        lg[j] = (c < cols) ? (acc[i][j] + out_b[v0 + c]) : -1e30f;
      }
      float lmax = fmaxf(lg[0], lg[1]);
#pragma unroll
      for (int off = 32; off; off >>= 1) lmax = fmaxf(lmax, __shfl_xor(lmax, off));
      float mn = fmaxf(m[i], lmax);
      float es = __expf(lg[0] - mn) + __expf(lg[1] - mn);
#pragma unroll
      for (int off = 32; off; off >>= 1) es += __shfl_xor(es, off);
      ssum[i] = ssum[i] * __expf(m[i] - mn) + es;
      m[i] = mn;
#pragma unroll
      for (int j = 0; j < 2; ++j) {
        int c = lane * 2 + j;
        if (c < cols && (v0 + c) == tgt[i]) tl[i] = lg[j];
      }
    }
  }
#pragma unroll
  for (int i = 0; i < 4; ++i) {
    float t_ = tl[i];
#pragma unroll
    for (int off = 32; off; off >>= 1) t_ = fmaxf(t_, __shfl_xor(t_, off));
    if (lane == 0) {
      float* p = part + (size_t)(vs * TB_ + r0 + wv * 4 + i) * 4;
      p[0] = m[i]; p[1] = ssum[i]; p[2] = t_;
    }
  }
}

// ---------------- K6: combine halves -> nll, mask, write out + reduce ----------------
__global__ __launch_bounds__(256) void combine_kernel(
    const float* __restrict__ part, const int* __restrict__ review_target,
    float* __restrict__ out0, float* __restrict__ accs) {
  int r = blockIdx.x * 256 + threadIdx.x;
  float nv = 0.f, mv = 0.f;
  if (r < TB_) {
    const float* p0 = part + (size_t)r * 4;
    const float* p1 = part + (size_t)(TB_ + r) * 4;
    float m0 = p0[0], s0 = p0[1], t0 = p0[2];
    float m1 = p1[0], s1 = p1[1], t1 = p1[2];
    float M = fmaxf(m0, m1);
    float S = s0 * expf(m0 - M) + s1 * expf(m1 - M);
    float lse = M + logf(S);
    float tlg = fmaxf(t0, t1);
    float nll = lse - tlg;
    float mask = (review_target[r] != 0) ? 1.f : 0.f;
    nv = nll * mask; mv = mask;
    out0[r] = nv;
  }
#pragma unroll
  for (int off = 32; off; off >>= 1) { nv += __shfl_xor(nv, off); mv += __shfl_xor(mv, off); }
  if ((threadIdx.x & 63) == 0) { atomicAdd(&accs[1], nv); atomicAdd(&accs[2], mv); }
}

// ---------------- K7: obj scalar ----------------
__global__ void obj_kernel(const float* __restrict__ accs, float* __restrict__ out_obj) {
  out_obj[0] = accs[0] + 1e-10f * (accs[1] / fmaxf(accs[2], 1.f));
}

extern "C" void kernel_launch(void* const* d_in, const int* in_sizes, int n_in,
                              void* d_out, int out_size, void* d_ws, size_t ws_size,
                              hipStream_t stream) {
  const int*   user          = (const int*)d_in[0];
  const int*   item          = (const int*)d_in[1];
  const float* label         = (const float*)d_in[2];
  const int*   review_input  = (const int*)d_in[3];
  const int*   review_target = (const int*)d_in[4];
  const int*   user_doc      = (const int*)d_in[5];
  const int*   item_doc      = (const int*)d_in[6];
  const float* gamma_user    = (const float*)d_in[7];
  const float* gamma_item    = (const float*)d_in[8];
  const float* theta_user    = (const float*)d_in[9];
  const float* theta_item    = (const float*)d_in[10];
  const float* doc_emb       = (const float*)d_in[11];
  const float* word_emb      = (const float*)d_in[12];
  const float* W_tu          = (const float*)d_in[13];
  const float* W_ti          = (const float*)d_in[14];
  const float* pred_W        = (const float*)d_in[15];
  const float* pred_b        = (const float*)d_in[16];
  const float* b_users       = (const float*)d_in[17];
  const float* b_items       = (const float*)d_in[18];
  const float* W_ih          = (const float*)d_in[19];
  const float* W_hh          = (const float*)d_in[20];
  const float* b_ih          = (const float*)d_in[21];
  const float* b_hh          = (const float*)d_in[22];
  const float* out_W         = (const float*)d_in[23];
  const float* out_b         = (const float*)d_in[24];

  float* f      = (float*)d_ws;
  float* ud     = f;                       // 25600
  float* idoc   = f + 25600;               // 25600
  float* gi_all = f + 51200;               // 4096*1536 = 6291456
  float* hbuf   = f + 6342656;             // 33*128*512 = 2162688
  float* part   = f + 8505344;             // 2*4096*4  = 32768
  float* accs   = f + 8538112;             // 8

  float* out0       = (float*)d_out;   // [4096] review_out_loss
  float* out_rating = out0 + 4096;     // [128]
  float* out_obj    = out0 + 4224;     // [1]

  hipMemsetAsync(hbuf, 0, (size_t)B_ * HD_ * sizeof(float), stream);  // h0 = 0
  hipMemsetAsync(accs, 0, 8 * sizeof(float), stream);

  doc_mean_kernel<<<256, 256, 0, stream>>>(user_doc, item_doc, doc_emb, ud, idoc);
  rating_kernel<<<128, 64, 0, stream>>>(user, item, label, gamma_user, gamma_item,
                                        theta_user, theta_item, ud, idoc, W_tu, W_ti,
                                        pred_W, pred_b, b_users, b_items, out_rating, accs);
  xw_gemm_kernel<<<64 * 24, 256, 0, stream>>>(review_input, user, item, word_emb,
                                              gamma_user, gamma_item, W_ih, b_ih, gi_all);
  for (int t = 0; t < T_; ++t)
    gru_step_kernel<<<64, 256, 0, stream>>>(gi_all, W_hh, b_hh, hbuf, t);
  vocab_lse_kernel<<<512, 256, 0, stream>>>(hbuf, out_W, out_b, review_target, part);
  combine_kernel<<<16, 256, 0, stream>>>(part, review_target, out0, accs);
  obj_kernel<<<1, 1, 0, stream>>>(accs, out_obj);
}

// Round 3
// 1628.198 us; speedup vs baseline: 8.4983x; 8.4983x over previous
//
#include <hip/hip_runtime.h>
#include <hip/hip_bf16.h>
#include <math.h>

#define B_ 128
#define T_ 32
#define V_ 30000
#define WD_ 512
#define MF_ 64
#define EWD_ 200
#define HD_ 512
#define DOC_ 500
#define GRU_IN_ 640
#define TB_ 4096     // T*B
#define NG_ 1536     // 3*HD
#define NTILES_ 1875 // V/16
#define NCHUNK_ 235  // ceil(V/128)

typedef __attribute__((ext_vector_type(8))) short bf16x8;
typedef __attribute__((ext_vector_type(4))) float f32x4;

#define GLOBAL_LOAD_LDS16(src, dst)                                              \
  __builtin_amdgcn_global_load_lds(                                              \
      (const __attribute__((address_space(1))) void*)(src),                      \
      (__attribute__((address_space(3))) void*)(dst), 16, 0, 0)

// ---------------- K1: ud/idoc = mean over DOC of doc_emb[doc] ----------------
__global__ __launch_bounds__(256) void doc_mean_kernel(
    const int* __restrict__ user_doc, const int* __restrict__ item_doc,
    const float* __restrict__ doc_emb, float* __restrict__ ud, float* __restrict__ idoc) {
  int b = blockIdx.x & 127;
  const int* doc = (blockIdx.x < 128) ? user_doc : item_doc;
  float* out = (blockIdx.x < 128) ? ud : idoc;
  int e = threadIdx.x;
  if (e >= EWD_) return;
  const int* row = doc + b * DOC_;
  float acc = 0.f;
#pragma unroll 4
  for (int d = 0; d < DOC_; ++d) {
    acc += doc_emb[row[d] * EWD_ + e];
  }
  out[b * EWD_ + e] = acc * (1.0f / DOC_);
}

// ---------------- K2: rating head ----------------
__global__ __launch_bounds__(64) void rating_kernel(
    const int* __restrict__ user, const int* __restrict__ item, const float* __restrict__ label,
    const float* __restrict__ gamma_user, const float* __restrict__ gamma_item,
    const float* __restrict__ theta_user, const float* __restrict__ theta_item,
    const float* __restrict__ ud, const float* __restrict__ idoc,
    const float* __restrict__ W_tu, const float* __restrict__ W_ti,
    const float* __restrict__ pred_W, const float* __restrict__ pred_b,
    const float* __restrict__ b_users, const float* __restrict__ b_items,
    float* __restrict__ out_rating, float* __restrict__ accs) {
  int b = blockIdx.x;
  int mf = threadIdx.x;  // 64 threads = 1 wave
  int u = user[b], it = item[b];
  float gu = gamma_user[u * MF_ + mf], gi = gamma_item[it * MF_ + mf];
  float tu = theta_user[u * MF_ + mf], ti = theta_item[it * MF_ + mf];
  float du = 0.f, di = 0.f;
#pragma unroll 4
  for (int e = 0; e < EWD_; ++e) {
    du += ud[b * EWD_ + e] * W_tu[mf * EWD_ + e];
    di += idoc[b * EWD_ + e] * W_ti[mf * EWD_ + e];
  }
  float c1 = gu * gi, c2 = tu * du, c3 = ti * di;
  float s = pred_W[mf] * c1 + pred_W[64 + mf] * c2 + pred_W[128 + mf] * c3;
#pragma unroll
  for (int off = 32; off; off >>= 1) s += __shfl_xor(s, off);
  if (mf == 0) {
    float pred = s + pred_b[0] + 3.5f + b_users[u] + b_items[it];
    float d = pred - label[b];
    float loss = d * d;
    out_rating[b] = loss;
    atomicAdd(&accs[0], loss);
  }
}

// ---------------- K3: gi_all = x_seq @ W_ih.T + b_ih (fused gather) ----------------
__global__ __launch_bounds__(256) void xw_gemm_kernel(
    const int* __restrict__ review_input, const int* __restrict__ user, const int* __restrict__ item,
    const float* __restrict__ word_emb, const float* __restrict__ gamma_user,
    const float* __restrict__ gamma_item, const float* __restrict__ W_ih,
    const float* __restrict__ b_ih, float* __restrict__ gi_all) {
  __shared__ float As[64][33];
  __shared__ float Bs[32][68];
  int m0 = (blockIdx.x & 63) * 64;   // 64 m-groups
  int n0 = (blockIdx.x >> 6) * 64;   // 24 n-groups
  int tid = threadIdx.x;
  int tc = tid & 15, tr = tid >> 4;  // 16x16 threads, each 4x4 outputs
  int kl = tid & 31, mb = tid >> 5;  // staging indices
  float acc[4][4] = {};
  for (int k0 = 0; k0 < GRU_IN_; k0 += 32) {
#pragma unroll
    for (int i = 0; i < 8; ++i) {
      int m = mb + i * 8;
      int r = m0 + m;
      int kg = k0 + kl;
      float v;
      if (kg < WD_) v = word_emb[review_input[r] * WD_ + kg];
      else if (kg < WD_ + MF_) v = gamma_user[user[r & 127] * MF_ + (kg - WD_)];
      else v = gamma_item[item[r & 127] * MF_ + (kg - WD_ - MF_)];
      As[m][kl] = v;
    }
#pragma unroll
    for (int i = 0; i < 8; ++i) {
      int n = mb + i * 8;
      Bs[kl][n] = W_ih[(n0 + n) * GRU_IN_ + k0 + kl];
    }
    __syncthreads();
#pragma unroll
    for (int k = 0; k < 32; ++k) {
      float4 b4 = *(const float4*)&Bs[k][tc * 4];
      float a0 = As[tr * 4 + 0][k], a1 = As[tr * 4 + 1][k];
      float a2 = As[tr * 4 + 2][k], a3 = As[tr * 4 + 3][k];
      acc[0][0] += a0 * b4.x; acc[0][1] += a0 * b4.y; acc[0][2] += a0 * b4.z; acc[0][3] += a0 * b4.w;
      acc[1][0] += a1 * b4.x; acc[1][1] += a1 * b4.y; acc[1][2] += a1 * b4.z; acc[1][3] += a1 * b4.w;
      acc[2][0] += a2 * b4.x; acc[2][1] += a2 * b4.y; acc[2][2] += a2 * b4.z; acc[2][3] += a2 * b4.w;
      acc[3][0] += a3 * b4.x; acc[3][1] += a3 * b4.y; acc[3][2] += a3 * b4.z; acc[3][3] += a3 * b4.w;
    }
    __syncthreads();
  }
  int n = n0 + tc * 4;
  float4 bb = *(const float4*)&b_ih[n];
#pragma unroll
  for (int i = 0; i < 4; ++i) {
    int r = m0 + tr * 4 + i;
    float4 o;
    o.x = acc[i][0] + bb.x; o.y = acc[i][1] + bb.y;
    o.z = acc[i][2] + bb.z; o.w = acc[i][3] + bb.w;
    *(float4*)&gi_all[(size_t)r * NG_ + n] = o;
  }
}

// ---------------- K4: one GRU step (launched 32x) ----------------
__global__ __launch_bounds__(256) void gru_step_kernel(
    const float* __restrict__ gi_all, const float* __restrict__ W_hh,
    const float* __restrict__ b_hh, float* __restrict__ hbuf, int t) {
  __shared__ float Hs[64][132];
  __shared__ float Ws[24][65];
  int j0 = blockIdx.x * 8;
  int tid = threadIdx.x;
  int tj = tid & 7, tb = tid >> 3;
  int lane = tid & 63, grp = tid >> 6;
  const float* hprev = hbuf + (size_t)t * B_ * HD_;
  float racc[4] = {}, zacc[4] = {}, nacc[4] = {};
  for (int k0 = 0; k0 < HD_; k0 += 64) {
#pragma unroll
    for (int i = 0; i < 32; ++i) {
      int b = grp * 32 + i;
      Hs[lane][b] = hprev[b * HD_ + k0 + lane];
    }
#pragma unroll
    for (int i = 0; i < 6; ++i) {
      int rr = grp + i * 4;
      int g = rr >> 3, jj = rr & 7;
      Ws[rr][lane] = W_hh[(g * HD_ + j0 + jj) * HD_ + k0 + lane];
    }
    __syncthreads();
#pragma unroll
    for (int k = 0; k < 64; ++k) {
      float4 h4 = *(const float4*)&Hs[k][tb * 4];
      float wr = Ws[tj][k], wz = Ws[8 + tj][k], wn = Ws[16 + tj][k];
      racc[0] += h4.x * wr; racc[1] += h4.y * wr; racc[2] += h4.z * wr; racc[3] += h4.w * wr;
      zacc[0] += h4.x * wz; zacc[1] += h4.y * wz; zacc[2] += h4.z * wz; zacc[3] += h4.w * wz;
      nacc[0] += h4.x * wn; nacc[1] += h4.y * wn; nacc[2] += h4.z * wn; nacc[3] += h4.w * wn;
    }
    __syncthreads();
  }
  int j = j0 + tj;
  float bh_r = b_hh[j], bh_z = b_hh[HD_ + j], bh_n = b_hh[2 * HD_ + j];
  float* hnext = hbuf + (size_t)(t + 1) * B_ * HD_;
#pragma unroll
  for (int i = 0; i < 4; ++i) {
    int b = tb * 4 + i;
    const float* gi_r = gi_all + (size_t)(t * B_ + b) * NG_;
    float ir = gi_r[j], iz = gi_r[HD_ + j], in_ = gi_r[2 * HD_ + j];
    float rg = 1.f / (1.f + expf(-(ir + racc[i] + bh_r)));
    float zg = 1.f / (1.f + expf(-(iz + zacc[i] + bh_z)));
    float ng = tanhf(in_ + rg * (nacc[i] + bh_n));
    float hp = hprev[b * HD_ + j];
    hnext[b * HD_ + j] = (1.f - zg) * ng + zg * hp;
  }
}

// ---------------- K5a: convert out_W (f32) -> B fragments (bf16, MFMA order) ----------------
// B_frags layout: [nt 0..1874][ks 0..15][lane 0..63][8 bf16]
// elem j of (nt,ks,lane): out_W[nt*16 + (lane&15)][ks*32 + (lane>>4)*8 + j]
__global__ __launch_bounds__(256) void conv_w_kernel(
    const float* __restrict__ out_W, __hip_bfloat16* __restrict__ Bf) {
  int idx = blockIdx.x * 256 + threadIdx.x;   // < 1875*16*64 = 1,920,000
  int l = idx & 63;
  int ks = (idx >> 6) & 15;
  int nt = idx >> 10;
  const float* src = out_W + (size_t)(nt * 16 + (l & 15)) * WD_ + ks * 32 + (l >> 4) * 8;
  __hip_bfloat16* dst = Bf + (size_t)idx * 8;
#pragma unroll
  for (int j = 0; j < 8; ++j) dst[j] = __float2bfloat16(src[j]);
}

// ---------------- K5b: convert h (f32) -> A fragments (bf16, MFMA order) ----------------
// A_frags layout: [mt 0..255][ks 0..15][lane][8]; row = mt*16+(lane&15) = t*128+b
__global__ __launch_bounds__(256) void conv_h_kernel(
    const float* __restrict__ hbuf, __hip_bfloat16* __restrict__ Af) {
  int idx = blockIdx.x * 256 + threadIdx.x;   // < 256*16*64 = 262,144
  int l = idx & 63;
  int ks = (idx >> 6) & 15;
  int mt = idx >> 10;
  int row = mt * 16 + (l & 15);
  int t = row >> 7, b = row & 127;
  const float* src = hbuf + ((size_t)(t + 1) * B_ + b) * HD_ + ks * 32 + (l >> 4) * 8;
  __hip_bfloat16* dst = Af + (size_t)idx * 8;
#pragma unroll
  for (int j = 0; j < 8; ++j) dst[j] = __float2bfloat16(src[j]);
}

// ---------------- K5c: exact target logits (fp32) ----------------
__global__ __launch_bounds__(256) void tgt_logit_kernel(
    const float* __restrict__ hbuf, const float* __restrict__ out_W,
    const float* __restrict__ out_b, const int* __restrict__ review_target,
    float* __restrict__ tl) {
  int r = blockIdx.x * 4 + (threadIdx.x >> 6);   // grid 1024
  int lane = threadIdx.x & 63;
  int t = r >> 7, b = r & 127;
  int tg = review_target[r];
  const float* h = hbuf + ((size_t)(t + 1) * B_ + b) * HD_;
  const float* w = out_W + (size_t)tg * WD_;
  float s = 0.f;
#pragma unroll
  for (int j = 0; j < 8; ++j) s += h[lane * 8 + j] * w[lane * 8 + j];
#pragma unroll
  for (int off = 32; off; off >>= 1) s += __shfl_xor(s, off);
  if (lane == 0) tl[r] = s + out_b[tg];
}

// ---------------- K5: MFMA vocab GEMM + fused sum-of-exp ----------------
// grid = 235 nchunks x 32 mblocks. Block: 128x128 tile, 256 thr = 4 waves (2x2).
// No max-tracking: |logit| <= ~5 analytically (|h|<=1, ||w_row||~0.2) -> exp safe.
__global__ __launch_bounds__(256) void vocab_gemm_kernel(
    const __hip_bfloat16* __restrict__ Af, const __hip_bfloat16* __restrict__ Bf,
    const float* __restrict__ out_b, float* __restrict__ part) {
  __shared__ char smem[32768];          // A: [0,16K) = 8mt x 2ks x 1KB; B: [16K,32K)
  __shared__ float ssum_sh[2][128];
  int mblk = blockIdx.x & 31;
  int nc = blockIdx.x >> 5;             // 0..234
  int tid = threadIdx.x, lane = tid & 63, wid = tid >> 6;
  int wr = wid >> 1, wc = wid & 1;
  int nt0 = nc * 8;
  const char* Ab = (const char*)Af;
  const char* Bb = (const char*)Bf;
  f32x4 acc[4][4];
#pragma unroll
  for (int mi = 0; mi < 4; ++mi)
#pragma unroll
    for (int ni = 0; ni < 4; ++ni) acc[mi][ni] = (f32x4){0.f, 0.f, 0.f, 0.f};

  for (int it = 0; it < 8; ++it) {      // BK = 64 (2 ksteps of 32)
    // stage 32 x 1KB chunks via global_load_lds; wave wid stages chunks wid*8..+7
#pragma unroll
    for (int i = 0; i < 8; ++i) {
      int c = wid * 8 + i;
      int j = c & 1;
      int half = c >> 1;                // 0..15
      if (half < 8) {                   // A chunk, mt = half
        int mtg = mblk * 8 + half;
        const char* src = Ab + (((size_t)mtg * 16 + it * 2 + j) << 10) + lane * 16;
        char* dst = (char*)smem + ((half * 2 + j) << 10);
        GLOBAL_LOAD_LDS16(src, dst);
      } else {                          // B chunk
        int bt = nt0 + (half - 8); if (bt > NTILES_ - 1) bt = NTILES_ - 1;
        const char* src = Bb + (((size_t)bt * 16 + it * 2 + j) << 10) + lane * 16;
        char* dst = (char*)smem + 16384 + (((half - 8) * 2 + j) << 10);
        GLOBAL_LOAD_LDS16(src, dst);
      }
    }
    __syncthreads();
#pragma unroll
    for (int j = 0; j < 2; ++j) {
      bf16x8 a[4], b[4];
#pragma unroll
      for (int mi = 0; mi < 4; ++mi)
        a[mi] = *(const bf16x8*)((const char*)smem + ((((wr * 4 + mi) * 2) + j) << 10) + lane * 16);
#pragma unroll
      for (int ni = 0; ni < 4; ++ni)
        b[ni] = *(const bf16x8*)((const char*)smem + 16384 + ((((wc * 4 + ni) * 2) + j) << 10) + lane * 16);
#pragma unroll
      for (int mi = 0; mi < 4; ++mi)
#pragma unroll
        for (int ni = 0; ni < 4; ++ni)
          acc[mi][ni] = __builtin_amdgcn_mfma_f32_16x16x32_bf16(a[mi], b[ni], acc[mi][ni], 0, 0, 0);
    }
    __syncthreads();
  }

  // epilogue: per-lane sum of exp over this block's 128 cols, then 16-lane reduce
  float bval[4];
  bool vld[4];
#pragma unroll
  for (int ni = 0; ni < 4; ++ni) {
    int nt = nt0 + wc * 4 + ni;
    vld[ni] = (nt < NTILES_);
    bval[ni] = vld[ni] ? out_b[nt * 16 + (lane & 15)] : 0.f;
  }
#pragma unroll
  for (int mi = 0; mi < 4; ++mi) {
    float s[4] = {0.f, 0.f, 0.f, 0.f};
#pragma unroll
    for (int ni = 0; ni < 4; ++ni) {
      if (vld[ni]) {
#pragma unroll
        for (int r = 0; r < 4; ++r) s[r] += __expf(acc[mi][ni][r] + bval[ni]);
      }
    }
#pragma unroll
    for (int r = 0; r < 4; ++r) {
#pragma unroll
      for (int off = 1; off < 16; off <<= 1) s[r] += __shfl_xor(s[r], off);
      if ((lane & 15) == 0)
        ssum_sh[wc][(wr * 4 + mi) * 16 + (lane >> 4) * 4 + r] = s[r];
    }
  }
  __syncthreads();
  if (tid < 128)
    part[(size_t)nc * TB_ + mblk * 128 + tid] = ssum_sh[0][tid] + ssum_sh[1][tid];
}

// ---------------- K6: combine partials -> nll, mask, out + reduce ----------------
__global__ __launch_bounds__(256) void combine_kernel(
    const float* __restrict__ part, const float* __restrict__ tl,
    const int* __restrict__ review_target, float* __restrict__ out0,
    float* __restrict__ accs) {
  int r = blockIdx.x * 256 + threadIdx.x;  // grid 16
  float S = 0.f;
  for (int nc = 0; nc < NCHUNK_; ++nc) S += part[(size_t)nc * TB_ + r];
  float nll = logf(S) - tl[r];
  float mask = (review_target[r] != 0) ? 1.f : 0.f;
  float nv = nll * mask, mv = mask;
  out0[r] = nv;
#pragma unroll
  for (int off = 32; off; off >>= 1) { nv += __shfl_xor(nv, off); mv += __shfl_xor(mv, off); }
  if ((threadIdx.x & 63) == 0) { atomicAdd(&accs[1], nv); atomicAdd(&accs[2], mv); }
}

// ---------------- K7: obj scalar ----------------
__global__ void obj_kernel(const float* __restrict__ accs, float* __restrict__ out_obj) {
  out_obj[0] = accs[0] + 1e-10f * (accs[1] / fmaxf(accs[2], 1.f));
}

extern "C" void kernel_launch(void* const* d_in, const int* in_sizes, int n_in,
                              void* d_out, int out_size, void* d_ws, size_t ws_size,
                              hipStream_t stream) {
  const int*   user          = (const int*)d_in[0];
  const int*   item          = (const int*)d_in[1];
  const float* label         = (const float*)d_in[2];
  const int*   review_input  = (const int*)d_in[3];
  const int*   review_target = (const int*)d_in[4];
  const int*   user_doc      = (const int*)d_in[5];
  const int*   item_doc      = (const int*)d_in[6];
  const float* gamma_user    = (const float*)d_in[7];
  const float* gamma_item    = (const float*)d_in[8];
  const float* theta_user    = (const float*)d_in[9];
  const float* theta_item    = (const float*)d_in[10];
  const float* doc_emb       = (const float*)d_in[11];
  const float* word_emb      = (const float*)d_in[12];
  const float* W_tu          = (const float*)d_in[13];
  const float* W_ti          = (const float*)d_in[14];
  const float* pred_W        = (const float*)d_in[15];
  const float* pred_b        = (const float*)d_in[16];
  const float* b_users       = (const float*)d_in[17];
  const float* b_items       = (const float*)d_in[18];
  const float* W_ih          = (const float*)d_in[19];
  const float* W_hh          = (const float*)d_in[20];
  const float* b_ih          = (const float*)d_in[21];
  const float* b_hh          = (const float*)d_in[22];
  const float* out_W         = (const float*)d_in[23];
  const float* out_b         = (const float*)d_in[24];

  float* f      = (float*)d_ws;
  float* ud     = f;                        // 25,600
  float* idoc   = f + 25600;                // 25,600
  float* gi_all = f + 51200;                // 6,291,456
  float* hbuf   = f + 6342656;              // 2,162,688 (33*128*512)
  float* accs   = f + 8505344;              // 8
  float* tl     = f + 8505352;              // 4,096
  float* part   = f + 8509448;              // 235*4096 = 962,560 -> ends 9,472,008
  __hip_bfloat16* Af = (__hip_bfloat16*)(f + 9472008);            // 4 MB (16B-aligned)
  __hip_bfloat16* Bf = (__hip_bfloat16*)((char*)Af + 4194304);    // 30.72 MB
  // total ws usage ~72.8 MB

  float* out0       = (float*)d_out;   // [4096] review_out_loss
  float* out_rating = out0 + 4096;     // [128]
  float* out_obj    = out0 + 4224;     // [1]

  hipMemsetAsync(hbuf, 0, (size_t)B_ * HD_ * sizeof(float), stream);  // h0 = 0
  hipMemsetAsync(accs, 0, 8 * sizeof(float), stream);

  doc_mean_kernel<<<256, 256, 0, stream>>>(user_doc, item_doc, doc_emb, ud, idoc);
  rating_kernel<<<128, 64, 0, stream>>>(user, item, label, gamma_user, gamma_item,
                                        theta_user, theta_item, ud, idoc, W_tu, W_ti,
                                        pred_W, pred_b, b_users, b_items, out_rating, accs);
  conv_w_kernel<<<7500, 256, 0, stream>>>(out_W, Bf);
  xw_gemm_kernel<<<64 * 24, 256, 0, stream>>>(review_input, user, item, word_emb,
                                              gamma_user, gamma_item, W_ih, b_ih, gi_all);
  for (int t = 0; t < T_; ++t)
    gru_step_kernel<<<64, 256, 0, stream>>>(gi_all, W_hh, b_hh, hbuf, t);
  conv_h_kernel<<<1024, 256, 0, stream>>>(hbuf, Af);
  tgt_logit_kernel<<<1024, 256, 0, stream>>>(hbuf, out_W, out_b, review_target, tl);
  vocab_gemm_kernel<<<NCHUNK_ * 32, 256, 0, stream>>>(Af, Bf, out_b, part);
  combine_kernel<<<16, 256, 0, stream>>>(part, tl, review_target, out0, accs);
  obj_kernel<<<1, 1, 0, stream>>>(accs, out_obj);
}

// Round 4
// 838.042 us; speedup vs baseline: 16.5110x; 1.9429x over previous
//
#include <hip/hip_runtime.h>
#include <hip/hip_bf16.h>
#include <math.h>

#define B_ 128
#define T_ 32
#define V_ 30000
#define WD_ 512
#define MF_ 64
#define EWD_ 200
#define HD_ 512
#define DOC_ 500
#define GRU_IN_ 640
#define TB_ 4096     // T*B
#define NG_ 1536     // 3*HD
#define NTILES_ 1875 // V/16
#define NCHUNK_ 235  // ceil(V/128)

typedef __attribute__((ext_vector_type(8))) short bf16x8;
typedef __attribute__((ext_vector_type(4))) float f32x4;

#define GLOBAL_LOAD_LDS16(src, dst)                                              \
  __builtin_amdgcn_global_load_lds(                                              \
      (const __attribute__((address_space(1))) void*)(src),                      \
      (__attribute__((address_space(3))) void*)(dst), 16, 0, 0)

__device__ inline float sigmoidf_(float x) { return 1.f / (1.f + __expf(-x)); }

// ---------------- K1: ud/idoc = mean over DOC of doc_emb[doc] ----------------
__global__ __launch_bounds__(256) void doc_mean_kernel(
    const int* __restrict__ user_doc, const int* __restrict__ item_doc,
    const float* __restrict__ doc_emb, float* __restrict__ ud, float* __restrict__ idoc) {
  int b = blockIdx.x & 127;
  const int* doc = (blockIdx.x < 128) ? user_doc : item_doc;
  float* out = (blockIdx.x < 128) ? ud : idoc;
  int e = threadIdx.x;
  if (e >= EWD_) return;
  const int* row = doc + b * DOC_;
  float acc = 0.f;
#pragma unroll 4
  for (int d = 0; d < DOC_; ++d) acc += doc_emb[row[d] * EWD_ + e];
  out[b * EWD_ + e] = acc * (1.0f / DOC_);
}

// ---------------- K2: rating head ----------------
__global__ __launch_bounds__(64) void rating_kernel(
    const int* __restrict__ user, const int* __restrict__ item, const float* __restrict__ label,
    const float* __restrict__ gamma_user, const float* __restrict__ gamma_item,
    const float* __restrict__ theta_user, const float* __restrict__ theta_item,
    const float* __restrict__ ud, const float* __restrict__ idoc,
    const float* __restrict__ W_tu, const float* __restrict__ W_ti,
    const float* __restrict__ pred_W, const float* __restrict__ pred_b,
    const float* __restrict__ b_users, const float* __restrict__ b_items,
    float* __restrict__ out_rating, float* __restrict__ accs) {
  int b = blockIdx.x;
  int mf = threadIdx.x;
  int u = user[b], it = item[b];
  float gu = gamma_user[u * MF_ + mf], gi = gamma_item[it * MF_ + mf];
  float tu = theta_user[u * MF_ + mf], ti = theta_item[it * MF_ + mf];
  float du = 0.f, di = 0.f;
#pragma unroll 4
  for (int e = 0; e < EWD_; ++e) {
    du += ud[b * EWD_ + e] * W_tu[mf * EWD_ + e];
    di += idoc[b * EWD_ + e] * W_ti[mf * EWD_ + e];
  }
  float c1 = gu * gi, c2 = tu * du, c3 = ti * di;
  float s = pred_W[mf] * c1 + pred_W[64 + mf] * c2 + pred_W[128 + mf] * c3;
#pragma unroll
  for (int off = 32; off; off >>= 1) s += __shfl_xor(s, off);
  if (mf == 0) {
    float pred = s + pred_b[0] + 3.5f + b_users[u] + b_items[it];
    float d = pred - label[b];
    out_rating[b] = d * d;
    atomicAdd(&accs[0], d * d);
  }
}

// ---------------- conv: out_W -> vocab B fragments ----------------
__global__ __launch_bounds__(256) void conv_w_kernel(
    const float* __restrict__ out_W, __hip_bfloat16* __restrict__ Bf) {
  int idx = blockIdx.x * 256 + threadIdx.x;   // < 1875*16*64
  int l = idx & 63;
  int ks = (idx >> 6) & 15;
  int nt = idx >> 10;
  const float* src = out_W + (size_t)(nt * 16 + (l & 15)) * WD_ + ks * 32 + (l >> 4) * 8;
  __hip_bfloat16* dst = Bf + (size_t)idx * 8;
#pragma unroll
  for (int j = 0; j < 8; ++j) dst[j] = __float2bfloat16(src[j]);
}

// ---------------- conv: x_seq (gathered) -> A fragments [mt 0..255][ks 0..19] ----------------
__global__ __launch_bounds__(256) void conv_x_kernel(
    const int* __restrict__ review_input, const int* __restrict__ user, const int* __restrict__ item,
    const float* __restrict__ word_emb, const float* __restrict__ gamma_user,
    const float* __restrict__ gamma_item, __hip_bfloat16* __restrict__ Xf) {
  int idx = blockIdx.x * 256 + threadIdx.x;   // < 256*20*64 = 327680
  int l = idx & 63;
  int q = idx >> 6;
  int ks = q % 20, mt = q / 20;
  int row = mt * 16 + (l & 15);
  int t = row >> 7, b = row & 127;
  int k0 = ks * 32 + (l >> 4) * 8;
  const float* src;
  if (k0 < WD_) src = word_emb + (size_t)review_input[t * B_ + b] * WD_ + k0;
  else if (k0 < WD_ + MF_) src = gamma_user + (size_t)user[b] * MF_ + (k0 - WD_);
  else src = gamma_item + (size_t)item[b] * MF_ + (k0 - WD_ - MF_);
  __hip_bfloat16* dst = Xf + (size_t)idx * 8;
#pragma unroll
  for (int j = 0; j < 8; ++j) dst[j] = __float2bfloat16(src[j]);
}

// ---------------- conv: W_ih -> B fragments [nt 0..95][ks 0..19] ----------------
__global__ __launch_bounds__(256) void conv_wih_kernel(
    const float* __restrict__ W_ih, __hip_bfloat16* __restrict__ Wf) {
  int idx = blockIdx.x * 256 + threadIdx.x;   // < 96*20*64 = 122880
  int l = idx & 63;
  int q = idx >> 6;
  int ks = q % 20, nt = q / 20;
  const float* src = W_ih + (size_t)(nt * 16 + (l & 15)) * GRU_IN_ + ks * 32 + (l >> 4) * 8;
  __hip_bfloat16* dst = Wf + (size_t)idx * 8;
#pragma unroll
  for (int j = 0; j < 8; ++j) dst[j] = __float2bfloat16(src[j]);
}

// ---------------- K3: gi_all = x_seq @ W_ih.T + b_ih  (MFMA, frag inputs) ----------------
// grid 384 = 32 mb x 12 nb. 128x128 tile, 4 waves 2x2, K=640 (10 it x 2 ks).
__global__ __launch_bounds__(256) void xw_mfma_kernel(
    const __hip_bfloat16* __restrict__ Xf, const __hip_bfloat16* __restrict__ Wf,
    const float* __restrict__ b_ih, float* __restrict__ gi_all) {
  __shared__ char smem[32768];
  int fb = blockIdx.x;
  int work = fb / 8 + (fb % 8) * 48;      // XCD swizzle (384 = 8*48)
  int mb = work / 12, nb = work % 12;
  int mt0 = mb * 8, nt0 = nb * 8;
  int tid = threadIdx.x, lane = tid & 63, wid = tid >> 6;
  int wr = wid >> 1, wc = wid & 1;
  const char* Ab = (const char*)Xf;
  const char* Bb = (const char*)Wf;
  f32x4 acc[4][4];
#pragma unroll
  for (int mi = 0; mi < 4; ++mi)
#pragma unroll
    for (int ni = 0; ni < 4; ++ni) acc[mi][ni] = (f32x4){0.f, 0.f, 0.f, 0.f};

  for (int it = 0; it < 10; ++it) {
#pragma unroll
    for (int i = 0; i < 8; ++i) {
      int c = wid * 8 + i;
      int j = c & 1, half = c >> 1;
      int ksg = it * 2 + j;
      if (half < 8) {
        const char* src = Ab + (((size_t)(mt0 + half) * 20 + ksg) << 10) + lane * 16;
        char* dst = (char*)smem + ((half * 2 + j) << 10);
        GLOBAL_LOAD_LDS16(src, dst);
      } else {
        const char* src = Bb + (((size_t)(nt0 + half - 8) * 20 + ksg) << 10) + lane * 16;
        char* dst = (char*)smem + 16384 + (((half - 8) * 2 + j) << 10);
        GLOBAL_LOAD_LDS16(src, dst);
      }
    }
    __syncthreads();
#pragma unroll
    for (int j = 0; j < 2; ++j) {
      bf16x8 a[4], b[4];
#pragma unroll
      for (int mi = 0; mi < 4; ++mi)
        a[mi] = *(const bf16x8*)((const char*)smem + ((((wr * 4 + mi) * 2) + j) << 10) + lane * 16);
#pragma unroll
      for (int ni = 0; ni < 4; ++ni)
        b[ni] = *(const bf16x8*)((const char*)smem + 16384 + ((((wc * 4 + ni) * 2) + j) << 10) + lane * 16);
#pragma unroll
      for (int mi = 0; mi < 4; ++mi)
#pragma unroll
        for (int ni = 0; ni < 4; ++ni)
          acc[mi][ni] = __builtin_amdgcn_mfma_f32_16x16x32_bf16(a[mi], b[ni], acc[mi][ni], 0, 0, 0);
    }
    __syncthreads();
  }
#pragma unroll
  for (int ni = 0; ni < 4; ++ni) {
    int col = (nt0 + wc * 4 + ni) * 16 + (lane & 15);
    float bb = b_ih[col];
#pragma unroll
    for (int mi = 0; mi < 4; ++mi) {
      int rbase = (mt0 + wr * 4 + mi) * 16 + (lane >> 4) * 4;
#pragma unroll
      for (int r = 0; r < 4; ++r)
        gi_all[(size_t)(rbase + r) * NG_ + col] = acc[mi][ni][r] + bb;
    }
  }
}

// ---------------- K4: ALL 32 GRU steps, persistent, MFMA ----------------
// 32 blocks x 256 thr. Block owns j-slice [j0, j0+16). W_hh frags resident in LDS.
// h state in registers (fp32); h_new written to hbuf (fp32 plain) + Afrag[t+1] (bf16 frags).
__global__ __launch_bounds__(256) void gru_all_kernel(
    const float* __restrict__ gi_all, const float* __restrict__ W_hh,
    const float* __restrict__ b_hh, float* __restrict__ hbuf,
    __hip_bfloat16* __restrict__ Afrag, int* __restrict__ bar) {
  __shared__ __align__(16) __hip_bfloat16 Wf[3 * 16 * 512];  // 48 KB
  __shared__ __align__(16) __hip_bfloat16 Lt[128][16];       // 4 KB
  int tid = threadIdx.x, lane = tid & 63, w = tid >> 6;
  int j0 = blockIdx.x * 16;
  int jloc = lane & 15;
  int j = j0 + jloc;
  int ks_h = j0 >> 5;             // A-frag ks for this j-slice
  int o8 = (j0 & 16) >> 3;        // 0 or 2: starting lane-group

  // prologue: W_hh -> bf16 fragments in LDS. 48 (g,ks) rows, 12 per wave.
#pragma unroll
  for (int i = 0; i < 12; ++i) {
    int rr = w * 12 + i;
    int g = rr >> 4, ks = rr & 15;
    const float* src = W_hh + (size_t)(g * HD_ + j0 + jloc) * HD_ + ks * 32 + (lane >> 4) * 8;
    __hip_bfloat16* dst = &Wf[(g * 16 + ks) * 512 + lane * 8];
#pragma unroll
    for (int q = 0; q < 8; ++q) dst[q] = __float2bfloat16(src[q]);
  }
  float bh0 = b_hh[j], bh1 = b_hh[HD_ + j], bh2 = b_hh[2 * HD_ + j];
  __syncthreads();

  float hreg[2][4] = {{0.f, 0.f, 0.f, 0.f}, {0.f, 0.f, 0.f, 0.f}};

  for (int t = 0; t < T_; ++t) {
    const __hip_bfloat16* As = Afrag + (size_t)t * 65536;
    f32x4 acc[2][3];
#pragma unroll
    for (int m = 0; m < 2; ++m)
#pragma unroll
      for (int g = 0; g < 3; ++g) acc[m][g] = (f32x4){0.f, 0.f, 0.f, 0.f};
#pragma unroll
    for (int ks = 0; ks < 16; ++ks) {
      bf16x8 a0 = *(const bf16x8*)(As + ((size_t)(2 * w + 0) * 16 + ks) * 512 + lane * 8);
      bf16x8 a1 = *(const bf16x8*)(As + ((size_t)(2 * w + 1) * 16 + ks) * 512 + lane * 8);
#pragma unroll
      for (int g = 0; g < 3; ++g) {
        bf16x8 bw = *(const bf16x8*)&Wf[(g * 16 + ks) * 512 + lane * 8];
        acc[0][g] = __builtin_amdgcn_mfma_f32_16x16x32_bf16(a0, bw, acc[0][g], 0, 0, 0);
        acc[1][g] = __builtin_amdgcn_mfma_f32_16x16x32_bf16(a1, bw, acc[1][g], 0, 0, 0);
      }
    }
    // epilogue: gates + h update
#pragma unroll
    for (int m = 0; m < 2; ++m) {
      int mt = 2 * w + m;
#pragma unroll
      for (int r = 0; r < 4; ++r) {
        int b = mt * 16 + (lane >> 4) * 4 + r;
        size_t rowoff = (size_t)(t * B_ + b) * NG_;
        float ir = gi_all[rowoff + j];
        float iz = gi_all[rowoff + HD_ + j];
        float in_ = gi_all[rowoff + 2 * HD_ + j];
        float rg = sigmoidf_(ir + acc[m][0][r] + bh0);
        float zg = sigmoidf_(iz + acc[m][1][r] + bh1);
        float ng = tanhf(in_ + rg * (acc[m][2][r] + bh2));
        float hn = (1.f - zg) * ng + zg * hreg[m][r];
        hreg[m][r] = hn;
        hbuf[(size_t)((t + 1) * B_ + b) * HD_ + j] = hn;
        Lt[b][jloc] = __float2bfloat16(hn);
      }
    }
    __syncthreads();
    // write h_new slice as A-fragments for step t+1 / vocab
    {
      int mt2 = tid >> 5, u = tid & 31;
      int bl = u & 15, hs = u >> 4;
      bf16x8 v = *(const bf16x8*)&Lt[mt2 * 16 + bl][hs * 8];
      int lp = bl + 16 * (o8 + hs);
      *(bf16x8*)(Afrag + (size_t)(t + 1) * 65536 + ((size_t)mt2 * 16 + ks_h) * 512 + lp * 8) = v;
    }
    __syncthreads();
    // device barrier (monotonic counter, bounded spin)
    if (tid == 0) {
      __threadfence();
      __hip_atomic_fetch_add(bar, 1, __ATOMIC_ACQ_REL, __HIP_MEMORY_SCOPE_AGENT);
      int target = 32 * (t + 1);
      int guard = 0;
      while (__hip_atomic_load(bar, __ATOMIC_ACQUIRE, __HIP_MEMORY_SCOPE_AGENT) < target &&
             ++guard < (1 << 26)) {
        __builtin_amdgcn_s_sleep(2);
      }
      __threadfence();
    }
    __syncthreads();
  }
}

// ---------------- K5c: exact target logits (fp32) ----------------
__global__ __launch_bounds__(256) void tgt_logit_kernel(
    const float* __restrict__ hbuf, const float* __restrict__ out_W,
    const float* __restrict__ out_b, const int* __restrict__ review_target,
    float* __restrict__ tl) {
  int r = blockIdx.x * 4 + (threadIdx.x >> 6);
  int lane = threadIdx.x & 63;
  int t = r >> 7, b = r & 127;
  int tg = review_target[r];
  const float* h = hbuf + ((size_t)(t + 1) * B_ + b) * HD_;
  const float* w = out_W + (size_t)tg * WD_;
  float s = 0.f;
#pragma unroll
  for (int q = 0; q < 8; ++q) s += h[lane * 8 + q] * w[lane * 8 + q];
#pragma unroll
  for (int off = 32; off; off >>= 1) s += __shfl_xor(s, off);
  if (lane == 0) tl[r] = s + out_b[tg];
}

// ---------------- K5: MFMA vocab GEMM + fused sum-of-exp ----------------
__global__ __launch_bounds__(256) void vocab_gemm_kernel(
    const __hip_bfloat16* __restrict__ Af, const __hip_bfloat16* __restrict__ Bf,
    const float* __restrict__ out_b, float* __restrict__ part) {
  __shared__ char smem[32768];
  __shared__ float ssum_sh[2][128];
  int fb = blockIdx.x;
  int work = fb / 8 + (fb % 8) * 940;   // XCD swizzle (7520 = 8*940)
  int mblk = work & 31;
  int nc = work >> 5;
  int tid = threadIdx.x, lane = tid & 63, wid = tid >> 6;
  int wr = wid >> 1, wc = wid & 1;
  int nt0 = nc * 8;
  const char* Ab = (const char*)Af;
  const char* Bb = (const char*)Bf;
  f32x4 acc[4][4];
#pragma unroll
  for (int mi = 0; mi < 4; ++mi)
#pragma unroll
    for (int ni = 0; ni < 4; ++ni) acc[mi][ni] = (f32x4){0.f, 0.f, 0.f, 0.f};

  for (int it = 0; it < 8; ++it) {
#pragma unroll
    for (int i = 0; i < 8; ++i) {
      int c = wid * 8 + i;
      int j = c & 1, half = c >> 1;
      if (half < 8) {
        int mtg = mblk * 8 + half;
        const char* src = Ab + (((size_t)mtg * 16 + it * 2 + j) << 10) + lane * 16;
        char* dst = (char*)smem + ((half * 2 + j) << 10);
        GLOBAL_LOAD_LDS16(src, dst);
      } else {
        int bt = nt0 + (half - 8); if (bt > NTILES_ - 1) bt = NTILES_ - 1;
        const char* src = Bb + (((size_t)bt * 16 + it * 2 + j) << 10) + lane * 16;
        char* dst = (char*)smem + 16384 + (((half - 8) * 2 + j) << 10);
        GLOBAL_LOAD_LDS16(src, dst);
      }
    }
    __syncthreads();
#pragma unroll
    for (int j = 0; j < 2; ++j) {
      bf16x8 a[4], b[4];
#pragma unroll
      for (int mi = 0; mi < 4; ++mi)
        a[mi] = *(const bf16x8*)((const char*)smem + ((((wr * 4 + mi) * 2) + j) << 10) + lane * 16);
#pragma unroll
      for (int ni = 0; ni < 4; ++ni)
        b[ni] = *(const bf16x8*)((const char*)smem + 16384 + ((((wc * 4 + ni) * 2) + j) << 10) + lane * 16);
#pragma unroll
      for (int mi = 0; mi < 4; ++mi)
#pragma unroll
        for (int ni = 0; ni < 4; ++ni)
          acc[mi][ni] = __builtin_amdgcn_mfma_f32_16x16x32_bf16(a[mi], b[ni], acc[mi][ni], 0, 0, 0);
    }
    __syncthreads();
  }

  float bval[4];
  bool vld[4];
#pragma unroll
  for (int ni = 0; ni < 4; ++ni) {
    int nt = nt0 + wc * 4 + ni;
    vld[ni] = (nt < NTILES_);
    bval[ni] = vld[ni] ? out_b[nt * 16 + (lane & 15)] : 0.f;
  }
#pragma unroll
  for (int mi = 0; mi < 4; ++mi) {
    float s[4] = {0.f, 0.f, 0.f, 0.f};
#pragma unroll
    for (int ni = 0; ni < 4; ++ni) {
      if (vld[ni]) {
#pragma unroll
        for (int r = 0; r < 4; ++r) s[r] += __expf(acc[mi][ni][r] + bval[ni]);
      }
    }
#pragma unroll
    for (int r = 0; r < 4; ++r) {
#pragma unroll
      for (int off = 1; off < 16; off <<= 1) s[r] += __shfl_xor(s[r], off);
      if ((lane & 15) == 0)
        ssum_sh[wc][(wr * 4 + mi) * 16 + (lane >> 4) * 4 + r] = s[r];
    }
  }
  __syncthreads();
  if (tid < 128)
    part[(size_t)nc * TB_ + mblk * 128 + tid] = ssum_sh[0][tid] + ssum_sh[1][tid];
}

// ---------------- K6: combine partials ----------------
__global__ __launch_bounds__(256) void combine_kernel(
    const float* __restrict__ part, const float* __restrict__ tl,
    const int* __restrict__ review_target, float* __restrict__ out0,
    float* __restrict__ accs) {
  int r = blockIdx.x * 256 + threadIdx.x;
  float S = 0.f;
  for (int nc = 0; nc < NCHUNK_; ++nc) S += part[(size_t)nc * TB_ + r];
  float nll = logf(S) - tl[r];
  float mask = (review_target[r] != 0) ? 1.f : 0.f;
  float nv = nll * mask, mv = mask;
  out0[r] = nv;
#pragma unroll
  for (int off = 32; off; off >>= 1) { nv += __shfl_xor(nv, off); mv += __shfl_xor(mv, off); }
  if ((threadIdx.x & 63) == 0) { atomicAdd(&accs[1], nv); atomicAdd(&accs[2], mv); }
}

// ---------------- K7: obj scalar ----------------
__global__ void obj_kernel(const float* __restrict__ accs, float* __restrict__ out_obj) {
  out_obj[0] = accs[0] + 1e-10f * (accs[1] / fmaxf(accs[2], 1.f));
}

extern "C" void kernel_launch(void* const* d_in, const int* in_sizes, int n_in,
                              void* d_out, int out_size, void* d_ws, size_t ws_size,
                              hipStream_t stream) {
  const int*   user          = (const int*)d_in[0];
  const int*   item          = (const int*)d_in[1];
  const float* label         = (const float*)d_in[2];
  const int*   review_input  = (const int*)d_in[3];
  const int*   review_target = (const int*)d_in[4];
  const int*   user_doc      = (const int*)d_in[5];
  const int*   item_doc      = (const int*)d_in[6];
  const float* gamma_user    = (const float*)d_in[7];
  const float* gamma_item    = (const float*)d_in[8];
  const float* theta_user    = (const float*)d_in[9];
  const float* theta_item    = (const float*)d_in[10];
  const float* doc_emb       = (const float*)d_in[11];
  const float* word_emb      = (const float*)d_in[12];
  const float* W_tu          = (const float*)d_in[13];
  const float* W_ti          = (const float*)d_in[14];
  const float* pred_W        = (const float*)d_in[15];
  const float* pred_b        = (const float*)d_in[16];
  const float* b_users       = (const float*)d_in[17];
  const float* b_items       = (const float*)d_in[18];
  const float* W_ih          = (const float*)d_in[19];
  const float* W_hh          = (const float*)d_in[20];
  const float* b_ih          = (const float*)d_in[21];
  const float* b_hh          = (const float*)d_in[22];
  const float* out_W         = (const float*)d_in[23];
  const float* out_b         = (const float*)d_in[24];

  float* f      = (float*)d_ws;
  float* ud     = f;                        // 25,600
  float* idoc   = f + 25600;                // 25,600
  float* gi_all = f + 51200;                // 6,291,456
  float* hbuf   = f + 6342656;              // 33*65536 = 2,162,688
  float* accs   = f + 8505344;              // 8
  int*   bar    = (int*)(f + 8505352);      // 4 ints
  float* tl     = f + 8505360;              // 4,096
  float* part   = f + 8509456;              // 235*4096 = 962,560 -> ends 9,472,016
  __hip_bfloat16* Afrag = (__hip_bfloat16*)(f + 9472016);          // 33 slots * 128KB = 4,325,376 B
  __hip_bfloat16* Bf    = (__hip_bfloat16*)((char*)Afrag + 4325376);   // 30,720,000 B
  __hip_bfloat16* Xf    = (__hip_bfloat16*)((char*)Bf + 30720000);     // 5,242,880 B
  __hip_bfloat16* WIf   = (__hip_bfloat16*)((char*)Xf + 5242880);      // 1,966,080 B
  // total ~80.2 MB

  float* out0       = (float*)d_out;   // [4096]
  float* out_rating = out0 + 4096;     // [128]
  float* out_obj    = out0 + 4224;     // [1]

  hipMemsetAsync(accs, 0, 32, stream);
  hipMemsetAsync(bar, 0, 16, stream);
  hipMemsetAsync(Afrag, 0, 131072, stream);   // slot 0 = h0 = 0

  doc_mean_kernel<<<256, 256, 0, stream>>>(user_doc, item_doc, doc_emb, ud, idoc);
  rating_kernel<<<128, 64, 0, stream>>>(user, item, label, gamma_user, gamma_item,
                                        theta_user, theta_item, ud, idoc, W_tu, W_ti,
                                        pred_W, pred_b, b_users, b_items, out_rating, accs);
  conv_w_kernel<<<7500, 256, 0, stream>>>(out_W, Bf);
  conv_x_kernel<<<1280, 256, 0, stream>>>(review_input, user, item, word_emb,
                                          gamma_user, gamma_item, Xf);
  conv_wih_kernel<<<480, 256, 0, stream>>>(W_ih, WIf);
  xw_mfma_kernel<<<384, 256, 0, stream>>>(Xf, WIf, b_ih, gi_all);
  gru_all_kernel<<<32, 256, 0, stream>>>(gi_all, W_hh, b_hh, hbuf, Afrag, bar);
  tgt_logit_kernel<<<1024, 256, 0, stream>>>(hbuf, out_W, out_b, review_target, tl);
  vocab_gemm_kernel<<<NCHUNK_ * 32, 256, 0, stream>>>(Afrag + 65536, Bf, out_b, part);
  combine_kernel<<<16, 256, 0, stream>>>(part, tl, review_target, out0, accs);
  obj_kernel<<<1, 1, 0, stream>>>(accs, out_obj);
}